// Round 2
// baseline (14.113 us; speedup 1.0000x reference)
//
#include <hip/hip_runtime.h>

#define N_IMG 16
#define M_PPL 30
#define K_JNT 17
#define S_DIM 16
#define HW (256 * 256)
#define IMG_STRIDE (K_JNT * HW)   // floats per image in tags

// One block per image. Computes pull/push/scale for image n and atomically
// accumulates (value/16) into out[0..2]. out must be zeroed before launch.
__global__ __launch_bounds__(512) void ae_fused(
    const float* __restrict__ tags,
    const int* __restrict__ joints,       // [N,M,K,2] int32 (loc, vis)
    const float* __restrict__ box_scales, // [N,M]
    const float* __restrict__ scale_dist, // [S]
    float* __restrict__ out)              // [3]
{
    const int n = blockIdx.x;
    const int t = threadIdx.x;
    const int m = t >> 4;   // person
    const int s = t & 15;   // scale index

    __shared__ float mean_sh[M_PPL][S_DIM];
    __shared__ float cnt_sh[M_PPL];
    __shared__ float pull_sh[M_PPL];
    __shared__ float dsc_sh[M_PPL];
    __shared__ float red_sh[8];

    if (m < M_PPL) {
        // Lane s owns joint k=s (int2 = loc,vis); joint 16 loaded uniformly.
        const int* jb = joints + ((n * M_PPL + m) * K_JNT) * 2;
        const int2 js  = ((const int2*)jb)[s];
        const int2 j16 = ((const int2*)jb)[16];
        const float sd = scale_dist[s];
        const float bs = box_scales[n * M_PPL + m];
        const float* tbase = tags + (size_t)n * IMG_STRIDE + s;

        float sum = 0.f, sum2 = 0.f, cnt = 0.f;
        #pragma unroll
        for (int k = 0; k < 16; ++k) {
            int loc = __shfl(js.x, k, 16);
            int vis = __shfl(js.y, k, 16);
            float g = tbase[(size_t)loc * S_DIM];
            float v = (vis > 0) ? 1.f : 0.f;
            sum  += v * g;
            sum2 += v * g * g;
            cnt  += v;
        }
        {
            float g = tbase[(size_t)j16.x * S_DIM];
            float v = (j16.y > 0) ? 1.f : 0.f;
            sum += v * g; sum2 += v * g * g; cnt += v;
        }

        const float safe_cnt = fmaxf(cnt, 1.f);
        const float mean = sum / safe_cnt;
        mean_sh[m][s] = mean;

        // sum_k vis*(g-mean)^2 == sum2 - cnt*mean^2  (since sum = cnt*mean)
        float p   = sum2 - cnt * mean * mean;
        float am  = fabsf(mean);
        float tgt = 1.f / (fabsf(bs - sd) + 1e-10f);
        float pr2 = am * am, tg2 = tgt * tgt, dt = am * tgt;
        #pragma unroll
        for (int o = 1; o < 16; o <<= 1) {
            p   += __shfl_xor(p, o);
            pr2 += __shfl_xor(pr2, o);
            tg2 += __shfl_xor(tg2, o);
            dt  += __shfl_xor(dt, o);
        }
        if (s == 0) {
            cnt_sh[m]  = cnt;
            pull_sh[m] = p / (safe_cnt * (float)S_DIM);
            float normP = fmaxf(sqrtf(pr2), 1e-12f);
            float normT = fmaxf(sqrtf(tg2), 1e-12f);
            dsc_sh[m]  = 1.f - dt / (normP * normT);
        }
    }
    __syncthreads();

    // Push: unordered pairs a<b (reference sums ordered pairs then *0.5 — equal).
    float psum = 0.f;
    for (int pidx = t; pidx < M_PPL * M_PPL; pidx += 512) {
        int a = pidx / M_PPL, b = pidx - a * M_PPL;
        if (a < b && cnt_sh[a] > 0.f && cnt_sh[b] > 0.f) {
            float d2 = 0.f;
            #pragma unroll
            for (int ss = 0; ss < S_DIM; ++ss) {
                float d = mean_sh[a][ss] - mean_sh[b][ss];
                d2 += d * d;
            }
            psum += __expf(-d2);
        }
    }
    #pragma unroll
    for (int o = 1; o < 64; o <<= 1) psum += __shfl_xor(psum, o);
    if ((t & 63) == 0) red_sh[t >> 6] = psum;

    // Per-person sums (valid-masked) in wave 0, lanes 0..31.
    float pullsum = 0.f, scsum = 0.f, nval = 0.f;
    if (t < 32) {
        bool v = (t < M_PPL) && (cnt_sh[t] > 0.f);
        pullsum = v ? pull_sh[t] : 0.f;
        scsum   = v ? dsc_sh[t]  : 0.f;
        nval    = v ? 1.f        : 0.f;
        #pragma unroll
        for (int o = 1; o < 32; o <<= 1) {
            pullsum += __shfl_xor(pullsum, o, 32);
            scsum   += __shfl_xor(scsum, o, 32);
            nval    += __shfl_xor(nval, o, 32);
        }
    }
    __syncthreads();

    if (t == 0) {
        float push_total = 0.f;
        #pragma unroll
        for (int w = 0; w < 8; ++w) push_total += red_sh[w];
        float safe_n = fmaxf(nval, 1.f);
        float push_img = (nval >= 2.f)
                           ? push_total / fmaxf(nval * (nval - 1.f), 1.f)
                           : 0.f;
        const float inv_n = 1.f / (float)N_IMG;
        atomicAdd(&out[0], pullsum / safe_n * inv_n);
        atomicAdd(&out[1], push_img * inv_n);
        atomicAdd(&out[2], scsum / safe_n * inv_n);
    }
}

extern "C" void kernel_launch(void* const* d_in, const int* in_sizes, int n_in,
                              void* d_out, int out_size, void* d_ws, size_t ws_size,
                              hipStream_t stream) {
    const float* tags       = (const float*)d_in[0];
    const int*   joints     = (const int*)d_in[1];
    const float* box_scales = (const float*)d_in[2];
    const float* scale_dist = (const float*)d_in[3];
    float* out = (float*)d_out;

    hipMemsetAsync(out, 0, 3 * sizeof(float), stream);
    ae_fused<<<N_IMG, 512, 0, stream>>>(tags, joints, box_scales, scale_dist, out);
}